// Round 14
// baseline (102.459 us; speedup 1.0000x reference)
//
#include <hip/hip_runtime.h>
#include <hip/hip_bf16.h>

#define DIM 128
#define NPB 512                 // nodes per bucket (pow2, shift 9)
#define NPB_SHIFT 9
// NN < 2^17 (=131072) required by the 17-bit src/dst packing; harness uses 100000.

#define A1_EPT 8
#define A1_EPB (256 * A1_EPT)   // 2048 edges per partition block
#define NBLK_STRIDE 512         // bhistT row stride (E <= 512*2048 = 1,048,576)

#define FROWS 64      // fused gather+finish: M-tile rows per block
#define FPAD 136      // bf16 row stride in LDS: 272B -> 2-way bank alias on b128 (free)

typedef __attribute__((ext_vector_type(8))) short bf16x8;
typedef __attribute__((ext_vector_type(8))) unsigned short u16x8;
typedef __attribute__((ext_vector_type(4))) float f32x4;

__device__ __forceinline__ short f2bf(float f) {
    union { __hip_bfloat16 h; short s; } u;
    u.h = __float2bfloat16(f);   // round-to-nearest-even
    return u.s;
}
__device__ __forceinline__ float bf2f(unsigned short s) {
    union { unsigned int u; float f; } c;
    c.u = ((unsigned int)s) << 16;
    return c.f;
}

__device__ __forceinline__ int load_dst(const void* eidx, int flag64, int E, int e) {
    return flag64 ? (int)((const long long*)eidx)[E + e] : ((const int*)eidx)[E + e];
}
__device__ __forceinline__ int load_src(const void* eidx, int flag64, int E, int e) {
    return flag64 ? (int)((const long long*)eidx)[e] : ((const int*)eidx)[e];
}

// Per-block int64/int32 self-detect (values < 2^17 => int64 high words of the
// first 128 entries are all zero; int32 data there is random node indices).
__device__ __forceinline__ int detect64_block(const unsigned int* e, int* sdet) {
    if (threadIdx.x == 0) {
        int ok64 = 1;
        for (int t = 0; t < 128; ++t) {
            if (e[2 * t + 1] != 0u) { ok64 = 0; break; }
        }
        *sdet = ok64;
    }
    __syncthreads();
    return *sdet;
}

// ---------------------------------------------------------------------------
// Prep (fused): cvt x f32 -> xb bf16 (pure stream, all blocks) + part1 bucket
// histogram (blocks < nblk: LDS hist of own 2048-edge chunk -> own bhistT row,
// uncontended).
// ---------------------------------------------------------------------------
__global__ __launch_bounds__(256) void prep_kernel(
        const float* __restrict__ x, unsigned short* __restrict__ xb, int n8,
        const void* __restrict__ eidx, int* __restrict__ bhistT, int E, int nblk) {
    __shared__ int bcnt[256];
    __shared__ int sdet;
    const int tid = threadIdx.x;
    const int blk = blockIdx.x;
    const bool hist = (blk < nblk);

    int f = 0;
    if (hist) {
        f = detect64_block((const unsigned int*)eidx, &sdet);
        bcnt[tid] = 0;
        __syncthreads();
        const int base = blk * A1_EPB;
        #pragma unroll
        for (int i = 0; i < A1_EPT; ++i) {
            int e = base + tid + i * 256;
            if (e < E) atomicAdd(&bcnt[load_dst(eidx, f, E, e) >> NPB_SHIFT], 1);
        }
    }

    const int stride = gridDim.x * blockDim.x;
    for (int t = blk * blockDim.x + tid; t < n8; t += stride) {
        const float4* pp = (const float4*)(x + (size_t)t * 8);
        float4 a = pp[0], b = pp[1];
        u16x8 o;
        o[0] = (unsigned short)f2bf(a.x); o[1] = (unsigned short)f2bf(a.y);
        o[2] = (unsigned short)f2bf(a.z); o[3] = (unsigned short)f2bf(a.w);
        o[4] = (unsigned short)f2bf(b.x); o[5] = (unsigned short)f2bf(b.y);
        o[6] = (unsigned short)f2bf(b.z); o[7] = (unsigned short)f2bf(b.w);
        *(u16x8*)(xb + (size_t)t * 8) = o;
    }

    if (hist) {
        __syncthreads();
        bhistT[tid * NBLK_STRIDE + blk] = bcnt[tid];   // uncontended own slot
    }
}

// ---------------------------------------------------------------------------
// scancol: one block per bucket; exclusive scan over the nblk block counts
// (in place) + colsum[bucket]. 512 threads, Hillis-Steele on 512 slots.
// ---------------------------------------------------------------------------
__global__ __launch_bounds__(512) void scancol_kernel(
        int* __restrict__ bhistT, int* __restrict__ colsum, int nblk) {
    __shared__ int s[512];
    const int tid = threadIdx.x;
    const int bu = blockIdx.x;
    int v = (tid < nblk) ? bhistT[bu * NBLK_STRIDE + tid] : 0;
    s[tid] = v;
    __syncthreads();
    for (int off = 1; off < 512; off <<= 1) {
        int t = (tid >= off) ? s[tid - off] : 0;
        __syncthreads();
        s[tid] += t;
        __syncthreads();
    }
    if (tid < nblk) bhistT[bu * NBLK_STRIDE + tid] = s[tid] - v;   // exclusive
    if (tid == 511) colsum[bu] = s[511];
}

// ---------------------------------------------------------------------------
// scanb (1 block): gstart = exclusive scan of colsum; gstart[NB] = E.
// ---------------------------------------------------------------------------
__global__ __launch_bounds__(256) void scanb_kernel(
        const int* __restrict__ colsum, int* __restrict__ gstart, int NB, int E) {
    __shared__ int s[256];
    const int tid = threadIdx.x;
    int val = (tid < NB) ? colsum[tid] : 0;
    s[tid] = val;
    __syncthreads();
    for (int off = 1; off < 256; off <<= 1) {
        int t = (tid >= off) ? s[tid - off] : 0;
        __syncthreads();
        s[tid] += t;
        __syncthreads();
    }
    if (tid < NB) gstart[tid] = s[tid] - val;
    if (tid == NB) gstart[NB] = E;   // NB < 256 guaranteed (NN < 2^17)
}

// ---------------------------------------------------------------------------
// part2: recompute LDS hist + scan + rank (deterministic), stage grouped by
// bucket (pk = w32[57:26] | dst_local[25:17] | src[16:0]), write runs at
// gstart[bu] + bhistT[bu][blk] + rank. ZERO global atomics.
// ---------------------------------------------------------------------------
__global__ __launch_bounds__(256) void part2_kernel(
        const void* __restrict__ eidx, const float* __restrict__ ew,
        const int* __restrict__ bhistT, const int* __restrict__ gstart,
        unsigned long long* __restrict__ srcw_tmp, int E) {
    __shared__ unsigned long long stage[A1_EPB];   // 16 KB
    __shared__ unsigned char sbid[A1_EPB];         //  2 KB
    __shared__ int bcnt[256], bscan[256], bcur[256], brun[256];
    __shared__ int sdet;
    const int tid = threadIdx.x;
    const int blk = blockIdx.x;
    const int base = blk * A1_EPB;
    const int f = detect64_block((const unsigned int*)eidx, &sdet);

    bcnt[tid] = 0;
    __syncthreads();

    unsigned long long pk[A1_EPT];
    unsigned char bid[A1_EPT];
    #pragma unroll
    for (int i = 0; i < A1_EPT; ++i) {
        int e = base + tid + i * 256;
        bid[i] = 0xFF;
        if (e < E) {
            int src = load_src(eidx, f, E, e);
            int dst = load_dst(eidx, f, E, e);
            unsigned int w = __float_as_uint(ew[e]);
            int b = dst >> NPB_SHIFT;
            pk[i] = ((unsigned long long)w << 26)
                  | ((unsigned long long)(dst & (NPB - 1)) << 17)
                  | (unsigned long long)(unsigned)src;
            bid[i] = (unsigned char)b;
            atomicAdd(&bcnt[b], 1);
        }
    }
    __syncthreads();

    // exclusive scan of bcnt (Hillis-Steele on 256)
    int val = bcnt[tid];
    bscan[tid] = val;
    __syncthreads();
    for (int off = 1; off < 256; off <<= 1) {
        int t = (tid >= off) ? bscan[tid - off] : 0;
        __syncthreads();
        bscan[tid] += t;
        __syncthreads();
    }
    int excl = bscan[tid] - val;
    __syncthreads();
    bscan[tid] = excl;        // now exclusive
    bcur[tid] = excl;
    // deterministic global run offset for this (block, bucket)
    brun[tid] = gstart[tid] + bhistT[tid * NBLK_STRIDE + blk];
    __syncthreads();

    // rank + stage (bucket-grouped)
    #pragma unroll
    for (int i = 0; i < A1_EPT; ++i) {
        if (bid[i] != 0xFF) {
            int slot = atomicAdd(&bcur[bid[i]], 1);
            stage[slot] = pk[i];
            sbid[slot] = bid[i];
        }
    }
    __syncthreads();

    int tot = (base + A1_EPB <= E) ? A1_EPB : (E - base);
    for (int s = tid; s < tot; s += 256) {
        int b = sbid[s];
        srcw_tmp[brun[b] + (s - bscan[b])] = stage[s];
    }
}

// ---------------------------------------------------------------------------
// A2 bucket-local sort (512 threads/block, 1 block/bucket): count per node
// (LDS), 512-wide scan, write node rowstart (coalesced), place final
// (w<<32|src) payloads. All payload writes land in the bucket's contiguous
// slot region from ONE block -> lines fill in L2 -> ~1x write amp.
// ---------------------------------------------------------------------------
__global__ __launch_bounds__(512) void sort_kernel(
        const unsigned long long* __restrict__ srcw_tmp,
        const int* __restrict__ gstart, unsigned long long* __restrict__ srcw,
        int* __restrict__ rowstart, int nn) {
    __shared__ int cnt[NPB], cur[NPB], s[NPB];
    const int tid = threadIdx.x;
    const int b = blockIdx.x;
    const int node0 = b << NPB_SHIFT;
    const int e0 = gstart[b], e1 = gstart[b + 1];

    cnt[tid] = 0;
    __syncthreads();
    for (int e = e0 + tid; e < e1; e += 512)
        atomicAdd(&cnt[(int)((srcw_tmp[e] >> 17) & (NPB - 1))], 1);
    __syncthreads();

    // exclusive scan over 512 (Hillis-Steele)
    int val = cnt[tid];
    s[tid] = val;
    __syncthreads();
    for (int off = 1; off < 512; off <<= 1) {
        int t = (tid >= off) ? s[tid - off] : 0;
        __syncthreads();
        s[tid] += t;
        __syncthreads();
    }
    int excl = s[tid] - val;
    cur[tid] = excl;
    __syncthreads();

    // node-level rowstart (coalesced, one per thread)
    int nbn = nn - node0; if (nbn > NPB) nbn = NPB;
    if (tid < nbn) rowstart[node0 + tid] = e0 + excl;

    // place payloads
    for (int e = e0 + tid; e < e1; e += 512) {
        unsigned long long pk = srcw_tmp[e];
        int dl = (int)((pk >> 17) & (NPB - 1));
        int pos = e0 + atomicAdd(&cur[dl], 1);
        srcw[pos] = ((pk >> 26) << 32) | (pk & 0x1FFFFULL);
    }
}

// ---------------------------------------------------------------------------
// FUSED gather + MFMA finish: one 512-thread block owns 64 nodes.
// Phase 1: node r = tid>>3 (8 lanes/node, lane owns 16 dims = 32B); 4-edge
//   zero-padded batches -> f32 acc -> normalize -> bf16 straight into the
//   MFMA staging LDS. No aggb intermediate (saves 51MB of HBM round trip).
// Phase 2: out = xb + alpha*(A_lds @ W^T + b)  [identical to proven finish;
//   C/D map col=lane&15, row=(lane>>4)*4+reg — verified learn_hip m89/m91]
// ---------------------------------------------------------------------------
__global__ __launch_bounds__(512) void gf_kernel(
        const unsigned short* __restrict__ xb, const uint2* __restrict__ srcw,
        const int* __restrict__ rowstart, float* __restrict__ out,
        const float* __restrict__ W, const float* __restrict__ bias,
        const float* __restrict__ alphaP, int nn, int E) {
    __shared__ alignas(16) unsigned short A_lds[FROWS * FPAD];   // 17408 B
    const int tid = threadIdx.x;
    const int b0  = blockIdx.x * FROWS;

    // ---------------- Phase 1: gather into A_lds ----------------
    {
        const int r  = tid >> 3;        // node row 0..63
        const int ls = tid & 7;         // owns dims [ls*16, ls*16+16)
        const int g  = b0 + r;
        float acc[16];
        #pragma unroll
        for (int j = 0; j < 16; ++j) acc[j] = 0.f;
        float inv = 1.0f;
        if (g < nn) {
            int n0 = rowstart[g];
            int n1 = (g + 1 < nn) ? rowstart[g + 1] : E;
            for (int e = n0; e < n1; e += 4) {
                int rem = n1 - e;
                uint2 sws[4];
                #pragma unroll
                for (int i = 0; i < 4; ++i) {
                    if (i < rem) sws[i] = srcw[e + i];
                    else { sws[i].x = 0u; sws[i].y = 0u; }   // w=0 pad
                }
                u16x8 lo[4], hi[4];
                #pragma unroll
                for (int i = 0; i < 4; ++i) {
                    const u16x8* xp = (const u16x8*)(xb + (size_t)sws[i].x * DIM + ls * 16);
                    lo[i] = xp[0];
                    hi[i] = xp[1];
                }
                #pragma unroll
                for (int i = 0; i < 4; ++i) {
                    float w = __uint_as_float(sws[i].y);
                    #pragma unroll
                    for (int j = 0; j < 8; ++j) {
                        acc[j]     = fmaf(bf2f(lo[i][j]), w, acc[j]);
                        acc[j + 8] = fmaf(bf2f(hi[i][j]), w, acc[j + 8]);
                    }
                }
            }
            inv = 1.0f / fmaxf((float)(n1 - n0), 1.0f);
        }
        u16x8 o0, o1;
        #pragma unroll
        for (int j = 0; j < 8; ++j) {
            o0[j] = (unsigned short)f2bf(acc[j] * inv);
            o1[j] = (unsigned short)f2bf(acc[j + 8] * inv);
        }
        *(u16x8*)&A_lds[r * FPAD + ls * 16] = o0;
        *(u16x8*)&A_lds[r * FPAD + ls * 16 + 8] = o1;
    }
    __syncthreads();

    // ---------------- Phase 2: MFMA + fused epilogue ----------------
    const int wv   = tid >> 6;          // wave 0..7
    const int lane = tid & 63;
    const int half = lane >> 4;         // 0..3
    const int l16  = lane & 15;
    const float alpha = alphaP[0];

    const int jcol = wv * 16 + l16;
    bf16x8 bfrag[4];
    #pragma unroll
    for (int kt = 0; kt < 4; ++kt) {
        const float4* w4 = (const float4*)(W + (size_t)jcol * DIM + kt * 32 + half * 8);
        float4 lo = w4[0], hi = w4[1];
        bf16x8 b;
        b[0] = f2bf(lo.x); b[1] = f2bf(lo.y); b[2] = f2bf(lo.z); b[3] = f2bf(lo.w);
        b[4] = f2bf(hi.x); b[5] = f2bf(hi.y); b[6] = f2bf(hi.z); b[7] = f2bf(hi.w);
        bfrag[kt] = b;
    }
    const float bias_j = bias[jcol];

    #pragma unroll
    for (int mt = 0; mt < 4; ++mt) {
        f32x4 acc = {0.f, 0.f, 0.f, 0.f};
        #pragma unroll
        for (int kt = 0; kt < 4; ++kt) {
            const bf16x8 a = *(const bf16x8*)&A_lds[(mt * 16 + l16) * FPAD + kt * 32 + half * 8];
            acc = __builtin_amdgcn_mfma_f32_16x16x32_bf16(a, bfrag[kt], acc, 0, 0, 0);
        }
        #pragma unroll
        for (int r = 0; r < 4; ++r) {
            int grow = b0 + mt * 16 + half * 4 + r;
            if (grow < nn) {
                size_t idx = (size_t)grow * DIM + jcol;
                out[idx] = bf2f(xb[idx]) + alpha * (acc[r] + bias_j);
            }
        }
    }
}

extern "C" void kernel_launch(void* const* d_in, const int* in_sizes, int n_in,
                              void* d_out, int out_size, void* d_ws, size_t ws_size,
                              hipStream_t stream) {
    // inputs: x(0), edge_index(1), num_nodes(2), edge_weight(3), W(4), b(5), alpha(6)
    const float* x      = (const float*)d_in[0];
    const void*  eidx   = d_in[1];
    const float* ew     = (const float*)d_in[3];
    const float* W      = (const float*)d_in[4];
    const float* bias   = (const float*)d_in[5];
    const float* alphaP = (const float*)d_in[6];

    const int NN = in_sizes[0] / DIM;       // < 2^17 required (harness: 100000)
    const int E  = in_sizes[3];
    const int NB = (NN + NPB - 1) / NPB;    // 196 buckets
    const int nblk = (E + A1_EPB - 1) / A1_EPB;   // 313 partition blocks (<= 512)

    // ws layout (~37 MB of 256 MB): xb u16[NN*DIM] | srcw u64[E]
    //   | srcw_tmp u64[E] | rowstart int[NN] | bhistT int[256*NBLK_STRIDE]
    //   | colsum[256] | gstart[257]
    unsigned short* xb = (unsigned short*)d_ws;
    unsigned long long* srcw     = (unsigned long long*)(xb + (size_t)NN * DIM);
    unsigned long long* srcw_tmp = srcw + E;
    int* rowstart = (int*)(srcw_tmp + E);
    int* bhistT   = rowstart + NN;
    int* colsum   = bhistT + 256 * NBLK_STRIDE;
    int* gstart   = colsum + 256;

    float* out = (float*)d_out;

    int n8 = NN * DIM / 8;
    prep_kernel<<<2048, 256, 0, stream>>>(x, xb, n8, eidx, bhistT, E, nblk);

    scancol_kernel<<<NB, 512, 0, stream>>>(bhistT, colsum, nblk);

    scanb_kernel<<<1, 256, 0, stream>>>(colsum, gstart, NB, E);

    part2_kernel<<<nblk, 256, 0, stream>>>(eidx, ew, bhistT, gstart, srcw_tmp, E);

    sort_kernel<<<NB, 512, 0, stream>>>(srcw_tmp, gstart, srcw, rowstart, NN);

    int fblocks = (NN + FROWS - 1) / FROWS;     // 1563
    gf_kernel<<<fblocks, 512, 0, stream>>>(xb, (const uint2*)srcw, rowstart,
                                           out, W, bias, alphaP, NN, E);
}